// Round 16
// baseline (1222.289 us; speedup 1.0000x reference)
//
#include <hip/hip_runtime.h>
#include <hip/hip_bf16.h>
#include <cstdint>

#define B_ 32
#define T_ 1024
#define E_ 256
#define H_ 256
#define G_ 1024
#define NTAG 14
#define LOG2E 1.4426950408889634f

typedef __bf16 bf8_t __attribute__((ext_vector_type(8)));
typedef float f4_t __attribute__((ext_vector_type(4)));
typedef int i4_t __attribute__((ext_vector_type(4)));
typedef unsigned short u16x4 __attribute__((ext_vector_type(4)));
typedef unsigned short u16x8 __attribute__((ext_vector_type(8)));

__device__ __forceinline__ unsigned short f2bf(float f) {
    unsigned u = __builtin_bit_cast(unsigned, f);
    u = u + 0x7FFFu + ((u >> 16) & 1u);
    return (unsigned short)(u >> 16);
}
__device__ __forceinline__ float bf2f(unsigned short s) {
    unsigned u = ((unsigned)s) << 16;
    return __builtin_bit_cast(float, u);
}
__device__ __forceinline__ bf8_t cvt8(float4 x, float4 y) {
    u16x8 u;
    u[0] = f2bf(x.x); u[1] = f2bf(x.y); u[2] = f2bf(x.z); u[3] = f2bf(x.w);
    u[4] = f2bf(y.x); u[5] = f2bf(y.y); u[6] = f2bf(y.z); u[7] = f2bf(y.w);
    return __builtin_bit_cast(bf8_t, u);
}
__device__ __forceinline__ bf8_t zero8() {
    u16x8 z = {0, 0, 0, 0, 0, 0, 0, 0};
    return __builtin_bit_cast(bf8_t, z);
}
__device__ __forceinline__ float fexp2(float x) { return __builtin_amdgcn_exp2f(x); }
__device__ __forceinline__ float frcp(float x) { return __builtin_amdgcn_rcpf(x); }
__device__ __forceinline__ float sigf(float x) {
    return frcp(1.0f + fexp2(-LOG2E * x));
}
__device__ __forceinline__ float tanh2_(float x) {
    return 1.0f - 2.0f * frcp(fexp2((2.0f * LOG2E) * x) + 1.0f);
}
__device__ __forceinline__ f4_t mfma16(bf8_t a, bf8_t b, f4_t c) {
    return __builtin_amdgcn_mfma_f32_16x16x32_bf16(a, b, c, 0, 0, 0);
}

// ---- fused xproj (+embedded gather, inline weight/bias cvt) + whh wquant tail blocks ----
// blocks 0..1023: xg4[d*16+b2][t][m 2][1024 n] = emb[sent] @ Wih^T + (bih+bhh)
// blocks 1024..1535: whh -> int8 per-row quant
__global__ __launch_bounds__(256, 1) void xproj_kernel(
        const int* sent, const float* emb,
        const float* wih_f, const float* wih_b,
        const float* bih_f, const float* bhh_f,
        const float* bih_b, const float* bhh_b,
        const float* whh_f, const float* whh_b,
        unsigned short* xg4, signed char* qw, float* sw) {
    int bid = blockIdx.x;
    int thr = threadIdx.x;
    int l = thr & 63, l15 = l & 15, lgp = l >> 4;

    if (bid >= 1024) {                   // ---- wquant: 4 rows per block ----
        int row = (bid - 1024) * 4 + (thr >> 6);   // 0..2047 = [d][1024]
        int d = row >> 10, rr = row & 1023;
        const float* src = (d ? whh_b : whh_f) + (size_t)rr * 256;
        float4 v = *reinterpret_cast<const float4*>(src + 4 * l);
        float am = fmaxf(fmaxf(fabsf(v.x), fabsf(v.y)), fmaxf(fabsf(v.z), fabsf(v.w)));
#pragma unroll
        for (int off = 1; off < 64; off <<= 1)
            am = fmaxf(am, __shfl_xor(am, off));
        am = fmaxf(am, 1e-20f);
        float inv = 127.f / am;
        int q0 = (int)__builtin_rintf(v.x * inv), q1 = (int)__builtin_rintf(v.y * inv);
        int q2 = (int)__builtin_rintf(v.z * inv), q3 = (int)__builtin_rintf(v.w * inv);
        unsigned u = (q0 & 255) | ((q1 & 255) << 8) | ((q2 & 255) << 16) | ((q3 & 255) << 24);
        *reinterpret_cast<unsigned*>(qw + (size_t)row * 256 + 4 * l) = u;
        if (l == 0) sw[row] = am / 127.f;
        return;
    }

    // ---- xproj ----
    int tt = bid & 63;                   // 0..63 (16 t each)
    int y = bid >> 6;                    // d*8 + bh*4 + ns
    int ns = y & 3, bh = (y >> 2) & 1, d = y >> 3;
    int w = thr >> 6;
    __shared__ unsigned short sh[256][16];

    // B fragments: wave's 64 n-cols x 256 k, converted f32->bf16 inline, pinned
    int nbase = ns * 256 + w * 64;
    const float* wd = (d ? wih_b : wih_f);
    const float* bihd = d ? bih_b : bih_f;
    const float* bhhd = d ? bhh_b : bhh_f;
    bf8_t breg[4][8];
    float bias[4];
#pragma unroll
    for (int p = 0; p < 4; ++p) {
        int n = nbase + 16 * p + l15;
        bias[p] = bihd[n] + bhhd[n];
        const float* brow = wd + (size_t)n * E_ + 8 * lgp;
#pragma unroll
        for (int ks = 0; ks < 8; ++ks) {
            float4 x = *reinterpret_cast<const float4*>(brow + 32 * ks);
            float4 z = *reinterpret_cast<const float4*>(brow + 32 * ks + 4);
            breg[p][ks] = cvt8(x, z);
        }
    }
#pragma unroll
    for (int p = 0; p < 4; ++p)
#pragma unroll
        for (int ks = 0; ks < 8; ++ks)
            asm volatile("" : "+v"(breg[p][ks]));

    int row16 = 16 * bh + l15;
    const int* sent_row = sent + (size_t)row16 * 1024 + tt * 16;

    for (int it = 0; it < 16; ++it) {
        int t = tt * 16 + it;
        int tok = sent_row[it];
        const float* erow = emb + (size_t)tok * E_ + 8 * lgp;
        bf8_t a[8];
#pragma unroll
        for (int ks = 0; ks < 8; ++ks) {
            float4 x = *reinterpret_cast<const float4*>(erow + 32 * ks);
            float4 z = *reinterpret_cast<const float4*>(erow + 32 * ks + 4);
            a[ks] = cvt8(x, z);
        }

        f4_t acc[4];
#pragma unroll
        for (int p = 0; p < 4; ++p) { acc[p][0] = 0.f; acc[p][1] = 0.f; acc[p][2] = 0.f; acc[p][3] = 0.f; }
#pragma unroll
        for (int p = 0; p < 4; ++p)
#pragma unroll
            for (int ks = 0; ks < 8; ++ks)
                acc[p] = mfma16(a[ks], breg[p][ks], acc[p]);

#pragma unroll
        for (int p = 0; p < 4; ++p)
#pragma unroll
            for (int r = 0; r < 4; ++r)
                sh[w * 64 + 16 * p + l15][4 * lgp + r] = f2bf(acc[p][r] + bias[p]);
        __syncthreads();
        int q = thr;
#pragma unroll
        for (int p = 0; p < 8; ++p) {
            int b2g = 8 * bh + p;
            size_t base = ((size_t)(d * 16 + b2g) * 1024 + t) * 2048 + ns * 256 + q;
            xg4[base]        = sh[q][2 * p];      // m=0
            xg4[base + 1024] = sh[q][2 * p + 1];  // m=1
        }
        __syncthreads();
    }
}

// ------- recurrence: 32 WGs = (dir, batch-pair); ALL weights in regs, 1 barrier/step ----
__global__ __launch_bounds__(512, 2) void lstm_kernel(const unsigned short* xg4,
        const signed char* qw, const float* sw, const float* h0, const float* c0,
        unsigned short* hs) {
    int bid = blockIdx.x;            // 0..31
    int b2 = bid & 15, d = bid >> 4;
    int tid = threadIdx.x;
    int w = tid >> 6, l = tid & 63, l15 = l & 15, lgp = l >> 4;

    __shared__ __attribute__((aligned(16))) signed char h8[2][2][320];
    __shared__ float red_sh[8];

    const signed char* qwd = qw + (size_t)d * 262144;

    i4_t wreg[4][2][4];
#pragma unroll
    for (int gt = 0; gt < 4; ++gt)
#pragma unroll
        for (int jt = 0; jt < 2; ++jt) {
            int n = 256 * gt + 32 * w + 16 * jt + l15;
#pragma unroll
            for (int ks = 0; ks < 4; ++ks)
                wreg[gt][jt][ks] = *reinterpret_cast<const i4_t*>(
                    qwd + (size_t)n * 256 + 64 * ks + 16 * lgp);
        }
#pragma unroll
    for (int gt = 0; gt < 4; ++gt)
#pragma unroll
        for (int jt = 0; jt < 2; ++jt)
#pragma unroll
            for (int ks = 0; ks < 4; ++ks)
                asm volatile("" : "+v"(wreg[gt][jt][ks]));   // keep resident

    int jt_c = lgp & 1, m_c = lgp >> 1;
    int j = 32 * w + 16 * jt_c + l15;

    float swv[4];
#pragma unroll
    for (int gt = 0; gt < 4; ++gt)
        swv[gt] = sw[d * 1024 + 256 * gt + j];
    float c = c0[((size_t)d * 32 + b2 * 2 + m_c) * 256 + j];

    int im = tid >> 8, ij = tid & 255;
    float v0 = h0[((size_t)d * 32 + b2 * 2 + im) * 256 + ij];
    float am = fabsf(v0);
#pragma unroll
    for (int off = 1; off < 64; off <<= 1)
        am = fmaxf(am, __shfl_xor(am, off));
    if (l == 0) red_sh[w] = am;
    __syncthreads();
    float bmax = red_sh[0];
#pragma unroll
    for (int q = 1; q < 8; ++q) bmax = fmaxf(bmax, red_sh[q]);
    bmax = fmaxf(bmax, 1e-20f);
    float s0 = bmax / 127.f;
    h8[1][im][ij] = (signed char)(int)__builtin_rintf(v0 * (127.f / bmax));

    float dq[4];
#pragma unroll
    for (int gt = 0; gt < 4; ++gt) dq[gt] = swv[gt] * s0;

    int t0 = d ? 1023 : 0;
    int xinc = d ? -2048 : 2048;
    int hinc = d ? -512 : 512;
    const unsigned short* xq = xg4 + ((size_t)(d * 16 + b2) * 1024 + t0) * 2048
                               + m_c * 1024 + j;
    unsigned short* hsp = hs + ((size_t)(b2 * 2 + m_c) * 1024 + t0) * 512 + d * 256 + j;

    unsigned short xc[4], xn[4];
#pragma unroll
    for (int gt = 0; gt < 4; ++gt) xc[gt] = xq[256 * gt];

    i4_t z4 = (i4_t){0, 0, 0, 0};
    asm volatile("" : "+v"(z4));

    __syncthreads();

    for (int s = 0; s < 1024; ++s) {
        int rp = (s + 1) & 1, wp = s & 1;

        if (s < 1023) {
            xq += xinc;
#pragma unroll
            for (int gt = 0; gt < 4; ++gt) xn[gt] = xq[256 * gt];
        }

        i4_t a[4];
#pragma unroll
        for (int ks = 0; ks < 4; ++ks)
            a[ks] = *reinterpret_cast<const i4_t*>(&h8[rp][l15 & 1][64 * ks + 16 * lgp]);

        i4_t acc[4][2];
#pragma unroll
        for (int gt = 0; gt < 4; ++gt)
#pragma unroll
            for (int jt = 0; jt < 2; ++jt) {
                acc[gt][jt] = __builtin_amdgcn_mfma_i32_16x16x64_i8(
                    a[0], wreg[gt][jt][0], z4, 0, 0, 0);
#pragma unroll
                for (int ks = 1; ks < 4; ++ks)
                    acc[gt][jt] = __builtin_amdgcn_mfma_i32_16x16x64_i8(
                        a[ks], wreg[gt][jt][ks], acc[gt][jt], 0, 0, 0);
            }

        int gi[4];
#pragma unroll
        for (int gt = 0; gt < 4; ++gt) {
            int e0 = jt_c ? acc[gt][1][0] : acc[gt][0][0];
            int e1 = jt_c ? acc[gt][1][1] : acc[gt][0][1];
            gi[gt] = m_c ? e1 : e0;
        }

        float pi = dq[0] * (float)gi[0] + bf2f(xc[0]);
        float pf = dq[1] * (float)gi[1] + bf2f(xc[1]);
        float pg = dq[2] * (float)gi[2] + bf2f(xc[2]);
        float po = dq[3] * (float)gi[3] + bf2f(xc[3]);
        float iv = sigf(pi), fv = sigf(pf), ov = sigf(po);
        float gv = tanh2_(pg);
        float cn = fv * c + iv * gv;
        c = cn;
        float hv = ov * tanh2_(cn);
        *hsp = f2bf(hv);
        hsp += hinc;
        h8[wp][m_c][j] = (signed char)(int)__builtin_rintf(hv * 127.f);

        if (s == 0) {
#pragma unroll
            for (int gt = 0; gt < 4; ++gt) dq[gt] = swv[gt] * (1.f / 127.f);
        }
#pragma unroll
        for (int gt = 0; gt < 4; ++gt) xc[gt] = xn[gt];

        asm volatile("s_waitcnt lgkmcnt(0)" ::: "memory");
        __builtin_amdgcn_sched_barrier(0);
        __builtin_amdgcn_s_barrier();
    }
}

// ---- fused logits+viterbi: 1 WG per sequence; Wout cvt inline; scan + backtrack ----
__global__ __launch_bounds__(256) void viterbi_kernel(const unsigned short* hs,
        const float* wout, const float* b_out, const float* crf,
        float* out) {
    int b = blockIdx.x;
    int tid = threadIdx.x;
    int ww = tid >> 6, l = tid & 63, l15 = l & 15, lgp = l >> 4;

    __shared__ float lg[1024][16];          // 64 KiB logits
    __shared__ unsigned char bp[1024][16];  // 16 KiB backpointers
    __shared__ unsigned char pth[1024];

    // ---- phase 1: logits = hs[b] @ Wout^T + b_out, into LDS (Wout cvt inline) ----
    float bo = (l15 < NTAG) ? b_out[l15] : 0.0f;
    bf8_t brow[16];
#pragma unroll
    for (int ks = 0; ks < 16; ++ks) {
        if (l15 < NTAG) {
            const float* wr = wout + (size_t)l15 * 512 + 32 * ks + 8 * lgp;
            float4 x = *reinterpret_cast<const float4*>(wr);
            float4 z = *reinterpret_cast<const float4*>(wr + 4);
            brow[ks] = cvt8(x, z);
        } else {
            brow[ks] = zero8();
        }
    }
    for (int k = 0; k < 16; ++k) {
        int mt = ww + 4 * k;                // 0..63 t-tiles of 16
        const unsigned short* arow = hs + ((size_t)b * 1024 + mt * 16 + l15) * 512 + 8 * lgp;
        f4_t acc; acc[0] = 0.f; acc[1] = 0.f; acc[2] = 0.f; acc[3] = 0.f;
#pragma unroll
        for (int ks = 0; ks < 16; ++ks) {
            bf8_t a = *reinterpret_cast<const bf8_t*>(arow + 32 * ks);
            acc = mfma16(a, brow[ks], acc);
        }
#pragma unroll
        for (int r = 0; r < 4; ++r)
            lg[mt * 16 + 4 * lgp + r][l15] = acc[r] + bo;
    }
    __syncthreads();

    // ---- phase 2: scan (wave 0 only), max3-tree + equality-mask argmax ----
    if (ww == 0) {
        int j = l;
        float crfj[NTAG];
#pragma unroll
        for (int i = 0; i < NTAG; ++i)
            crfj[i] = (j < NTAG) ? crf[i * NTAG + j] : 0.0f;
        float v = (j < NTAG) ? lg[0][j] : -3.0e38f;
        for (int t = 1; t < 1024; ++t) {
            float sv[NTAG];
#pragma unroll
            for (int i = 0; i < NTAG; ++i)
                sv[i] = __shfl(v, i) + crfj[i];
            float m0 = fmaxf(fmaxf(sv[0], sv[1]), sv[2]);
            float m1 = fmaxf(fmaxf(sv[3], sv[4]), sv[5]);
            float m2 = fmaxf(fmaxf(sv[6], sv[7]), sv[8]);
            float m3 = fmaxf(fmaxf(sv[9], sv[10]), sv[11]);
            float m4 = fmaxf(sv[12], sv[13]);
            float best = fmaxf(fmaxf(fmaxf(m0, m1), fmaxf(m2, m3)), m4);
            unsigned msk = 0;
#pragma unroll
            for (int i = 0; i < NTAG; ++i)
                msk |= (sv[i] == best) ? (1u << i) : 0u;
            int arg = __builtin_ctz(msk);
            float lt = (j < NTAG) ? lg[t][j] : 0.0f;
            v = (j < NTAG) ? (lt + best) : -3.0e38f;
            if (j < 16) bp[t][j] = (unsigned char)arg;
        }
        float best = -3.0e38f; int tag = 0;
#pragma unroll
        for (int jj = 0; jj < NTAG; ++jj) {
            float s = __shfl(v, jj);
            if (s > best) { best = s; tag = jj; }
        }
        if (j == 0) {
            out[b] = best;
            int tg = tag;
            pth[1023] = (unsigned char)tg;
            for (int t = 1023; t >= 1; --t) {
                tg = bp[t][tg];
                pth[t - 1] = (unsigned char)tg;
            }
        }
    }
    __syncthreads();
    float* pout = out + 32 + (size_t)b * 1024;
    for (int t = tid; t < 1024; t += 256)
        pout[t] = (float)pth[t];
}

extern "C" void kernel_launch(void* const* d_in, const int* in_sizes, int n_in,
                              void* d_out, int out_size, void* d_ws, size_t ws_size,
                              hipStream_t stream) {
    const int* sent = (const int*)d_in[0];
    const float* emb = (const float*)d_in[1];
    const float* wih_f = (const float*)d_in[2];
    const float* whh_f = (const float*)d_in[3];
    const float* bih_f = (const float*)d_in[4];
    const float* bhh_f = (const float*)d_in[5];
    const float* wih_b = (const float*)d_in[6];
    const float* whh_b = (const float*)d_in[7];
    const float* bih_b = (const float*)d_in[8];
    const float* bhh_b = (const float*)d_in[9];
    const float* h0 = (const float*)d_in[10];
    const float* c0 = (const float*)d_in[11];
    const float* wout = (const float*)d_in[12];
    const float* b_out = (const float*)d_in[13];
    const float* crf = (const float*)d_in[14];

    char* ws = (char*)d_ws;
    signed char* qw       = (signed char*)(ws + 0);               // 512 KiB
    float* sw             = (float*)(ws + 524288);                // 8 KiB
    unsigned short* xg4   = (unsigned short*)(ws + 18898944);     // 128 MiB
    unsigned short* hs    = (unsigned short*)(ws + 153116672);    // 32 MiB
    float* out = (float*)d_out;

    hipLaunchKernelGGL(xproj_kernel, dim3(1536), dim3(256), 0, stream,
                       sent, emb, wih_f, wih_b, bih_f, bhh_f, bih_b, bhh_b,
                       whh_f, whh_b, xg4, qw, sw);
    hipLaunchKernelGGL(lstm_kernel, dim3(32), dim3(512), 0, stream,
                       xg4, qw, sw, h0, c0, hs);
    hipLaunchKernelGGL(viterbi_kernel, dim3(32), dim3(256), 0, stream,
                       hs, wout, b_out, crf, out);
}

// Round 17
// 1175.504 us; speedup vs baseline: 1.0398x; 1.0398x over previous
//
#include <hip/hip_runtime.h>
#include <hip/hip_bf16.h>
#include <cstdint>

#define B_ 32
#define T_ 1024
#define E_ 256
#define H_ 256
#define G_ 1024
#define NTAG 14
#define LOG2E 1.4426950408889634f

typedef __bf16 bf8_t __attribute__((ext_vector_type(8)));
typedef float f4_t __attribute__((ext_vector_type(4)));
typedef int i4_t __attribute__((ext_vector_type(4)));
typedef unsigned short u16x4 __attribute__((ext_vector_type(4)));

__device__ __forceinline__ unsigned short f2bf(float f) {
    unsigned u = __builtin_bit_cast(unsigned, f);
    u = u + 0x7FFFu + ((u >> 16) & 1u);
    return (unsigned short)(u >> 16);
}
__device__ __forceinline__ float bf2f(unsigned short s) {
    unsigned u = ((unsigned)s) << 16;
    return __builtin_bit_cast(float, u);
}
__device__ __forceinline__ float fexp2(float x) { return __builtin_amdgcn_exp2f(x); }
__device__ __forceinline__ float frcp(float x) { return __builtin_amdgcn_rcpf(x); }
__device__ __forceinline__ float sigf(float x) {
    return frcp(1.0f + fexp2(-LOG2E * x));
}
__device__ __forceinline__ float tanh2_(float x) {
    return 1.0f - 2.0f * frcp(fexp2((2.0f * LOG2E) * x) + 1.0f);
}
__device__ __forceinline__ f4_t mfma16(bf8_t a, bf8_t b, f4_t c) {
    return __builtin_amdgcn_mfma_f32_16x16x32_bf16(a, b, c, 0, 0, 0);
}

// ------- setup: embed gather + whh int8 quant + wih bf16 + biases + wout pad ----
__global__ __launch_bounds__(256) void setup_kernel(
        const int* sent, const float* emb,
        const float* whh_f, const float* whh_b,
        const float* wih_f, const float* wih_b,
        const float* bih_f, const float* bhh_f,
        const float* bih_b, const float* bhh_b,
        const float* wout,
        unsigned short* xbf, signed char* qw, float* sw,
        unsigned short* wih_bf, float* biasc, unsigned short* wout_bf) {
    int bid = blockIdx.x, thr = threadIdx.x;
    if (bid < 8192) {                         // embed: 32768 rows x 64 lanes
        int tid = bid * 256 + thr;
        int bt = tid >> 6;
        int e0 = (tid & 63) << 2;
        int tok = sent[bt];
        float4 v = *reinterpret_cast<const float4*>(emb + (size_t)tok * E_ + e0);
        u16x4 o;
        o[0] = f2bf(v.x); o[1] = f2bf(v.y); o[2] = f2bf(v.z); o[3] = f2bf(v.w);
        *reinterpret_cast<u16x4*>(xbf + (size_t)bt * E_ + e0) = o;
        return;
    }
    if (bid < 8704) {                         // wquant: rows [d][1024], per-row scale
        int row = (bid - 8192) * 4 + (thr >> 6);
        int l = thr & 63;
        int d = row >> 10, rr = row & 1023;
        const float* src = (d ? whh_b : whh_f) + (size_t)rr * 256;
        float4 v = *reinterpret_cast<const float4*>(src + 4 * l);
        float am = fmaxf(fmaxf(fabsf(v.x), fabsf(v.y)), fmaxf(fabsf(v.z), fabsf(v.w)));
#pragma unroll
        for (int off = 1; off < 64; off <<= 1)
            am = fmaxf(am, __shfl_xor(am, off));
        am = fmaxf(am, 1e-20f);
        float inv = 127.f / am;
        int q0 = (int)__builtin_rintf(v.x * inv), q1 = (int)__builtin_rintf(v.y * inv);
        int q2 = (int)__builtin_rintf(v.z * inv), q3 = (int)__builtin_rintf(v.w * inv);
        unsigned u = (q0 & 255) | ((q1 & 255) << 8) | ((q2 & 255) << 16) | ((q3 & 255) << 24);
        *reinterpret_cast<unsigned*>(qw + (size_t)row * 256 + 4 * l) = u;
        if (l == 0) sw[row] = am / 127.f;
        return;
    }
    int tid = (bid - 8704) * 256 + thr;       // prep: 534528 work items
    if (tid < 524288) {
        int d = tid >> 18, off = tid & 262143;
        wih_bf[tid] = f2bf((d ? wih_b : wih_f)[off]);
        return;
    }
    int t2 = tid - 524288;
    if (t2 < 8192) {
        int n = t2 >> 9, k = t2 & 511;
        wout_bf[t2] = (n < NTAG) ? f2bf(wout[n * 512 + k]) : (unsigned short)0;
        return;
    }
    int t3 = t2 - 8192;
    if (t3 < 2048) {
        int d = t3 >> 10, g = t3 & 1023;
        biasc[t3] = d ? (bih_b[g] + bhh_b[g]) : (bih_f[g] + bhh_f[g]);
    }
}

// ---- input projection -> xg4[d*16+b2][t][m 2][1024 n]; B pinned in regs, 16-t loop ----
__global__ __launch_bounds__(256, 2) void xproj_kernel(const unsigned short* xbf,
        const unsigned short* wih_bf, const float* biasc, unsigned short* xg4) {
    int tt = blockIdx.x;                 // 0..63 (16 t each)
    int y = blockIdx.y;                  // d*8 + bh*4 + ns
    int ns = y & 3, bh = (y >> 2) & 1, d = y >> 3;
    int w = threadIdx.x >> 6, l = threadIdx.x & 63;
    int l15 = l & 15, lgp = l >> 4;
    __shared__ unsigned short sh[256][16];

    int nbase = ns * 256 + w * 64;
    const unsigned short* wd = wih_bf + (size_t)d * 262144;
    bf8_t breg[4][8];
    float bias[4];
#pragma unroll
    for (int p = 0; p < 4; ++p) {
        int n = nbase + 16 * p + l15;
        bias[p] = biasc[d * G_ + n];
        const unsigned short* brow = wd + (size_t)n * E_ + 8 * lgp;
#pragma unroll
        for (int ks = 0; ks < 8; ++ks)
            breg[p][ks] = *reinterpret_cast<const bf8_t*>(brow + 32 * ks);
    }
#pragma unroll
    for (int p = 0; p < 4; ++p)
#pragma unroll
        for (int ks = 0; ks < 8; ++ks)
            asm volatile("" : "+v"(breg[p][ks]));

    const unsigned short* arow =
        xbf + ((size_t)(16 * bh + l15) * 1024 + tt * 16) * E_ + 8 * lgp;

    for (int it = 0; it < 16; ++it) {
        int t = tt * 16 + it;
        bf8_t a[8];
#pragma unroll
        for (int ks = 0; ks < 8; ++ks)
            a[ks] = *reinterpret_cast<const bf8_t*>(arow + 32 * ks);
        arow += 256;

        f4_t acc[4];
#pragma unroll
        for (int p = 0; p < 4; ++p) { acc[p][0] = 0.f; acc[p][1] = 0.f; acc[p][2] = 0.f; acc[p][3] = 0.f; }
#pragma unroll
        for (int p = 0; p < 4; ++p)
#pragma unroll
            for (int ks = 0; ks < 8; ++ks)
                acc[p] = mfma16(a[ks], breg[p][ks], acc[p]);

#pragma unroll
        for (int p = 0; p < 4; ++p)
#pragma unroll
            for (int r = 0; r < 4; ++r)
                sh[w * 64 + 16 * p + l15][4 * lgp + r] = f2bf(acc[p][r] + bias[p]);
        __syncthreads();
        int q = threadIdx.x;
#pragma unroll
        for (int p = 0; p < 8; ++p) {
            int b2g = 8 * bh + p;
            size_t base = ((size_t)(d * 16 + b2g) * 1024 + t) * 2048 + ns * 256 + q;
            xg4[base]        = sh[q][2 * p];      // m=0
            xg4[base + 1024] = sh[q][2 * p + 1];  // m=1
        }
        __syncthreads();
    }
}

// ------- recurrence: 32 WGs = (dir, batch-pair); ALL weights in regs, 1 barrier/step ----
__global__ __launch_bounds__(512, 2) void lstm_kernel(const unsigned short* xg4,
        const signed char* qw, const float* sw, const float* h0, const float* c0,
        unsigned short* hs) {
    int bid = blockIdx.x;            // 0..31
    int b2 = bid & 15, d = bid >> 4;
    int tid = threadIdx.x;
    int w = tid >> 6, l = tid & 63, l15 = l & 15, lgp = l >> 4;

    __shared__ __attribute__((aligned(16))) signed char h8[2][2][320];
    __shared__ float red_sh[8];

    const signed char* qwd = qw + (size_t)d * 262144;

    i4_t wreg[4][2][4];
#pragma unroll
    for (int gt = 0; gt < 4; ++gt)
#pragma unroll
        for (int jt = 0; jt < 2; ++jt) {
            int n = 256 * gt + 32 * w + 16 * jt + l15;
#pragma unroll
            for (int ks = 0; ks < 4; ++ks)
                wreg[gt][jt][ks] = *reinterpret_cast<const i4_t*>(
                    qwd + (size_t)n * 256 + 64 * ks + 16 * lgp);
        }
#pragma unroll
    for (int gt = 0; gt < 4; ++gt)
#pragma unroll
        for (int jt = 0; jt < 2; ++jt)
#pragma unroll
            for (int ks = 0; ks < 4; ++ks)
                asm volatile("" : "+v"(wreg[gt][jt][ks]));   // keep resident

    int jt_c = lgp & 1, m_c = lgp >> 1;
    int j = 32 * w + 16 * jt_c + l15;

    float swv[4];
#pragma unroll
    for (int gt = 0; gt < 4; ++gt)
        swv[gt] = sw[d * 1024 + 256 * gt + j];
    float c = c0[((size_t)d * 32 + b2 * 2 + m_c) * 256 + j];

    int im = tid >> 8, ij = tid & 255;
    float v0 = h0[((size_t)d * 32 + b2 * 2 + im) * 256 + ij];
    float am = fabsf(v0);
#pragma unroll
    for (int off = 1; off < 64; off <<= 1)
        am = fmaxf(am, __shfl_xor(am, off));
    if (l == 0) red_sh[w] = am;
    __syncthreads();
    float bmax = red_sh[0];
#pragma unroll
    for (int q = 1; q < 8; ++q) bmax = fmaxf(bmax, red_sh[q]);
    bmax = fmaxf(bmax, 1e-20f);
    float s0 = bmax / 127.f;
    h8[1][im][ij] = (signed char)(int)__builtin_rintf(v0 * (127.f / bmax));

    float dq[4];
#pragma unroll
    for (int gt = 0; gt < 4; ++gt) dq[gt] = swv[gt] * s0;

    int t0 = d ? 1023 : 0;
    int xinc = d ? -2048 : 2048;
    int hinc = d ? -512 : 512;
    const unsigned short* xq = xg4 + ((size_t)(d * 16 + b2) * 1024 + t0) * 2048
                               + m_c * 1024 + j;
    unsigned short* hsp = hs + ((size_t)(b2 * 2 + m_c) * 1024 + t0) * 512 + d * 256 + j;

    unsigned short xc[4], xn[4];
#pragma unroll
    for (int gt = 0; gt < 4; ++gt) xc[gt] = xq[256 * gt];

    i4_t z4 = (i4_t){0, 0, 0, 0};
    asm volatile("" : "+v"(z4));

    __syncthreads();

    for (int s = 0; s < 1024; ++s) {
        int rp = (s + 1) & 1, wp = s & 1;

        if (s < 1023) {
            xq += xinc;
#pragma unroll
            for (int gt = 0; gt < 4; ++gt) xn[gt] = xq[256 * gt];
        }

        i4_t a[4];
#pragma unroll
        for (int ks = 0; ks < 4; ++ks)
            a[ks] = *reinterpret_cast<const i4_t*>(&h8[rp][l15 & 1][64 * ks + 16 * lgp]);

        i4_t acc[4][2];
#pragma unroll
        for (int gt = 0; gt < 4; ++gt)
#pragma unroll
            for (int jt = 0; jt < 2; ++jt) {
                acc[gt][jt] = __builtin_amdgcn_mfma_i32_16x16x64_i8(
                    a[0], wreg[gt][jt][0], z4, 0, 0, 0);
#pragma unroll
                for (int ks = 1; ks < 4; ++ks)
                    acc[gt][jt] = __builtin_amdgcn_mfma_i32_16x16x64_i8(
                        a[ks], wreg[gt][jt][ks], acc[gt][jt], 0, 0, 0);
            }

        int gi[4];
#pragma unroll
        for (int gt = 0; gt < 4; ++gt) {
            int e0 = jt_c ? acc[gt][1][0] : acc[gt][0][0];
            int e1 = jt_c ? acc[gt][1][1] : acc[gt][0][1];
            gi[gt] = m_c ? e1 : e0;
        }

        float pi = dq[0] * (float)gi[0] + bf2f(xc[0]);
        float pf = dq[1] * (float)gi[1] + bf2f(xc[1]);
        float pg = dq[2] * (float)gi[2] + bf2f(xc[2]);
        float po = dq[3] * (float)gi[3] + bf2f(xc[3]);
        float iv = sigf(pi), fv = sigf(pf), ov = sigf(po);
        float gv = tanh2_(pg);
        float cn = fv * c + iv * gv;
        c = cn;
        float hv = ov * tanh2_(cn);
        *hsp = f2bf(hv);
        hsp += hinc;
        h8[wp][m_c][j] = (signed char)(int)__builtin_rintf(hv * 127.f);

        if (s == 0) {
#pragma unroll
            for (int gt = 0; gt < 4; ++gt) dq[gt] = swv[gt] * (1.f / 127.f);
        }
#pragma unroll
        for (int gt = 0; gt < 4; ++gt) xc[gt] = xn[gt];

        asm volatile("s_waitcnt lgkmcnt(0)" ::: "memory");
        __builtin_amdgcn_sched_barrier(0);
        __builtin_amdgcn_s_barrier();
    }
}

// ---- fused logits+viterbi: 1 WG per sequence; logits -> LDS, then scan + backtrack ----
__global__ __launch_bounds__(512) void viterbi_kernel(const unsigned short* hs,
        const unsigned short* wout_bf, const float* b_out, const float* crf,
        float* out) {
    int b = blockIdx.x;
    int tid = threadIdx.x;
    int ww = tid >> 6, l = tid & 63, l15 = l & 15, lgp = l >> 4;

    __shared__ float lg[1024][16];          // 64 KiB logits
    __shared__ unsigned char bp[1024][16];  // 16 KiB backpointers
    __shared__ unsigned char pth[1024];

    // ---- phase 1: logits = hs[b] @ Wout^T + b_out, into LDS (8 waves) ----
    float bo = (l15 < NTAG) ? b_out[l15] : 0.0f;
    const unsigned short* brow = wout_bf + (size_t)l15 * 512 + 8 * lgp;
    for (int k = 0; k < 8; ++k) {
        int mt = ww + 8 * k;                // 0..63 t-tiles of 16
        const unsigned short* arow = hs + ((size_t)b * 1024 + mt * 16 + l15) * 512 + 8 * lgp;
        f4_t acc; acc[0] = 0.f; acc[1] = 0.f; acc[2] = 0.f; acc[3] = 0.f;
#pragma unroll
        for (int ks = 0; ks < 16; ++ks) {
            bf8_t a = *reinterpret_cast<const bf8_t*>(arow + 32 * ks);
            bf8_t bb = *reinterpret_cast<const bf8_t*>(brow + 32 * ks);
            acc = mfma16(a, bb, acc);
        }
#pragma unroll
        for (int r = 0; r < 4; ++r)
            lg[mt * 16 + 4 * lgp + r][l15] = acc[r] + bo;
    }
    __syncthreads();

    // ---- phase 2: scan (wave 0 only), max3-tree + equality-mask argmax ----
    if (ww == 0) {
        int j = l;
        float crfj[NTAG];
#pragma unroll
        for (int i = 0; i < NTAG; ++i)
            crfj[i] = (j < NTAG) ? crf[i * NTAG + j] : 0.0f;
        float v = (j < NTAG) ? lg[0][j] : -3.0e38f;
        for (int t = 1; t < 1024; ++t) {
            float sv[NTAG];
#pragma unroll
            for (int i = 0; i < NTAG; ++i)
                sv[i] = __shfl(v, i) + crfj[i];
            float m0 = fmaxf(fmaxf(sv[0], sv[1]), sv[2]);
            float m1 = fmaxf(fmaxf(sv[3], sv[4]), sv[5]);
            float m2 = fmaxf(fmaxf(sv[6], sv[7]), sv[8]);
            float m3 = fmaxf(fmaxf(sv[9], sv[10]), sv[11]);
            float m4 = fmaxf(sv[12], sv[13]);
            float best = fmaxf(fmaxf(fmaxf(m0, m1), fmaxf(m2, m3)), m4);
            unsigned msk = 0;
#pragma unroll
            for (int i = 0; i < NTAG; ++i)
                msk |= (sv[i] == best) ? (1u << i) : 0u;
            int arg = __builtin_ctz(msk);
            float lt = (j < NTAG) ? lg[t][j] : 0.0f;
            v = (j < NTAG) ? (lt + best) : -3.0e38f;
            if (j < 16) bp[t][j] = (unsigned char)arg;
        }
        float best = -3.0e38f; int tag = 0;
#pragma unroll
        for (int jj = 0; jj < NTAG; ++jj) {
            float s = __shfl(v, jj);
            if (s > best) { best = s; tag = jj; }
        }
        if (j == 0) {
            out[b] = best;
            int tg = tag;
            pth[1023] = (unsigned char)tg;
            for (int t = 1023; t >= 1; --t) {
                tg = bp[t][tg];
                pth[t - 1] = (unsigned char)tg;
            }
        }
    }
    __syncthreads();
    float* pout = out + 32 + (size_t)b * 1024;
    for (int t = tid; t < 1024; t += 512)
        pout[t] = (float)pth[t];
}

extern "C" void kernel_launch(void* const* d_in, const int* in_sizes, int n_in,
                              void* d_out, int out_size, void* d_ws, size_t ws_size,
                              hipStream_t stream) {
    const int* sent = (const int*)d_in[0];
    const float* emb = (const float*)d_in[1];
    const float* wih_f = (const float*)d_in[2];
    const float* whh_f = (const float*)d_in[3];
    const float* bih_f = (const float*)d_in[4];
    const float* bhh_f = (const float*)d_in[5];
    const float* wih_b = (const float*)d_in[6];
    const float* whh_b = (const float*)d_in[7];
    const float* bih_b = (const float*)d_in[8];
    const float* bhh_b = (const float*)d_in[9];
    const float* h0 = (const float*)d_in[10];
    const float* c0 = (const float*)d_in[11];
    const float* wout = (const float*)d_in[12];
    const float* b_out = (const float*)d_in[13];
    const float* crf = (const float*)d_in[14];

    char* ws = (char*)d_ws;
    signed char* qw       = (signed char*)(ws + 0);               // 512 KiB
    float* sw             = (float*)(ws + 524288);                // 8 KiB
    unsigned short* wih_bf = (unsigned short*)(ws + 1048576);     // 1 MiB
    float* biasc          = (float*)(ws + 2097152);               // 8 KiB
    unsigned short* wout_bf = (unsigned short*)(ws + 2105344);    // 16 KiB
    unsigned short* xbf   = (unsigned short*)(ws + 2121728);      // 16 MiB
    unsigned short* xg4   = (unsigned short*)(ws + 18898944);     // 128 MiB
    unsigned short* hs    = (unsigned short*)(ws + 153116672);    // 32 MiB
    float* out = (float*)d_out;

    hipLaunchKernelGGL(setup_kernel, dim3(10792), dim3(256), 0, stream,
                       sent, emb, whh_f, whh_b, wih_f, wih_b,
                       bih_f, bhh_f, bih_b, bhh_b, wout,
                       xbf, qw, sw, wih_bf, biasc, wout_bf);
    hipLaunchKernelGGL(xproj_kernel, dim3(64, 16), dim3(256), 0, stream,
                       xbf, wih_bf, biasc, xg4);
    hipLaunchKernelGGL(lstm_kernel, dim3(32), dim3(512), 0, stream,
                       xg4, qw, sw, h0, c0, hs);
    hipLaunchKernelGGL(viterbi_kernel, dim3(32), dim3(512), 0, stream,
                       hs, wout_bf, b_out, crf, out);
}